// Round 2
// baseline (118.835 us; speedup 1.0000x reference)
//
#include <hip/hip_runtime.h>
#include <hip/hip_bf16.h>

// Preisach hysteresis, N=256 mesh, M=4096 steps.
// Row-compressed state: row i is +1 for j<c_i, -1 for c_i<=j<=i (single int c_i).
//   up event (hc>hp):   c_i = i+1 for all i with lin[i] < hc   (iup = #lin<hc)
//   down event (hc<hp): c_i = min(c_i, jdn), jdn = #lin<=hc
// b[t] = (2*sum_i Pref[i][c_i(t)] - Stot) / Stot,  Pref = row-exclusive prefix of softplus density.
// Init state (reference's wrap-around t=0 step, hc=1.0): rows 0..254 all +1, row 255 all -1.

#define NN 256
#define MM 4096
#define LSTEPS 16   // time steps per block in main kernel

// ws layout (bytes):
//   0     : int   codes[MM]            (16384 B)
//   16384 : float pref[NN*(NN+3)/2]    (33152 floats = 132608 B)

__device__ __forceinline__ int rowOff(int i) { return i * (i + 3) / 2; }

// K1: softplus density, per-row exclusive prefix sums.
__global__ __launch_bounds__(NN) void k_prefix(const float* __restrict__ raw,
                                               float* __restrict__ pref) {
    int i = blockIdx.x, t = threadIdx.x;
    float sp = 0.f;
    if (t <= i) {
        float x = raw[i * (i + 1) / 2 + t];
        sp = (x > 20.f) ? x : log1pf(expf(x));
    }
    __shared__ float buf[NN];
    buf[t] = sp;
    __syncthreads();
    for (int o = 1; o < NN; o <<= 1) {
        float add = (t >= o) ? buf[t - o] : 0.f;
        __syncthreads();
        buf[t] += add;
        __syncthreads();
    }
    int base = rowOff(i);
    if (t == 0) pref[base] = 0.f;
    if (t <= i) pref[base + t + 1] = buf[t];   // exclusive prefix: Pref[c]=sum_{j<c}
    // pref[base + i + 1] == row total (tail sp = 0 beyond t=i)
}

// K2: per-step event codes. code = (iup<<16) | jdn; up: jdn=0xFFFF; down: iup=0; no-op: both.
__global__ void k_codes(const float* __restrict__ h, const float* __restrict__ lin,
                        int* __restrict__ codes) {
    int k = blockIdx.x * blockDim.x + threadIdx.x;
    if (k >= MM) return;
    float hc = h[k];
    float hp = (k == 0) ? 1.0f : h[k - 1];   // hs[0] = -H_MIN = 1.0
    int code;
    if (hc > hp) {
        int lo = 0, hi = NN;                  // iup = first idx with lin >= hc
        while (lo < hi) { int mid = (lo + hi) >> 1; if (lin[mid] < hc) lo = mid + 1; else hi = mid; }
        code = (lo << 16) | 0xFFFF;
    } else if (hc < hp) {
        int lo = 0, hi = NN;                  // jdn = first idx with lin > hc
        while (lo < hi) { int mid = (lo + hi) >> 1; if (lin[mid] <= hc) lo = mid + 1; else hi = mid; }
        code = lo;                            // iup = 0
    } else {
        code = 0xFFFF;                        // no event
    }
    codes[k] = code;
}

// K3: each block owns time window [T, T+LSTEPS). Reconstruct c(T) by backward scan,
// then forward steps with prefix-table gathers + block reduction.
__global__ __launch_bounds__(NN) void k_main(const int* __restrict__ codes,
                                             const float* __restrict__ pref,
                                             float* __restrict__ out) {
    __shared__ int sc[MM];      // 16 KB: all step codes
    __shared__ float sTot[4];
    __shared__ float sPart[4];
    int tid = threadIdx.x;
    int i = tid;                // thread == row
    int T = blockIdx.x * LSTEPS;

    for (int k = tid; k < MM; k += NN) sc[k] = codes[k];

    int base = rowOff(i);
    float rowtot = pref[base + i + 1];
    {   // block-reduce row totals -> Stot (every thread ends with the same value)
        float v = rowtot;
        v += __shfl_xor(v, 1);  v += __shfl_xor(v, 2);  v += __shfl_xor(v, 4);
        v += __shfl_xor(v, 8);  v += __shfl_xor(v, 16); v += __shfl_xor(v, 32);
        if ((tid & 63) == 0) sTot[tid >> 6] = v;
    }
    __syncthreads();
    float stot = sTot[0] + sTot[1] + sTot[2] + sTot[3];
    float inv = 1.0f / stot;

    // Backward scan: find c_i(T). Row 255 never up-flips -> c = 0 always.
    int runmin = i + 1;         // initial c_i(0) = i+1 folded in (rows 0..254 all +1)
    int c = (i == NN - 1) ? 0 : i + 1;
    bool done = (i == NN - 1);
    for (int k = T - 1; k >= 0; --k) {
        if (__all(done)) break;             // wave-level early exit
        int code = sc[k];
        if (!done) {
            runmin = min(runmin, code & 0xFFFF);                 // down events accumulate
            if (i < (code >> 16)) { c = runmin; done = true; }   // last covering up event
        }
    }
    if (!done) c = runmin;      // reached t=0 with no covering up event

    for (int kk = 0; kk < LSTEPS; ++kk) {
        int k = T + kk;
        int code = sc[k];
        int iup = code >> 16, jdn = code & 0xFFFF;
        c = (i < iup) ? (i + 1) : min(c, jdn);
        float v = pref[base + c];
        // wave64 reduce
        v += __shfl_xor(v, 1);  v += __shfl_xor(v, 2);  v += __shfl_xor(v, 4);
        v += __shfl_xor(v, 8);  v += __shfl_xor(v, 16); v += __shfl_xor(v, 32);
        if ((tid & 63) == 0) sPart[tid >> 6] = v;
        __syncthreads();
        if (tid == 0) {
            float s = sPart[0] + sPart[1] + sPart[2] + sPart[3];
            out[k] = (2.f * s - stot) * inv;
        }
        __syncthreads();
    }
}

extern "C" void kernel_launch(void* const* d_in, const int* in_sizes, int n_in,
                              void* d_out, int out_size, void* d_ws, size_t ws_size,
                              hipStream_t stream) {
    const float* h   = (const float*)d_in[0];   // (M,)
    const float* raw = (const float*)d_in[1];   // (N*(N+1)/2,)
    const float* xx  = (const float*)d_in[2];   // (N,N): row 0 is lin[0..N)
    // d_in[3] = yy (lin along rows) — not needed.

    int*   codes = (int*)d_ws;
    float* pref  = (float*)((char*)d_ws + MM * sizeof(int));

    k_prefix<<<NN, NN, 0, stream>>>(raw, pref);
    k_codes<<<MM / 256, 256, 0, stream>>>(h, xx, codes);
    k_main<<<MM / LSTEPS, NN, 0, stream>>>(codes, pref, (float*)d_out);
}

// Round 3
// 99.949 us; speedup vs baseline: 1.1890x; 1.1890x over previous
//
#include <hip/hip_runtime.h>
#include <hip/hip_bf16.h>

// Preisach hysteresis, N=256 mesh, M=4096 steps.
// Row-compressed state: row i is +1 for j<c_i, -1 for c_i<=j<=i (single int c_i).
//   up event (hc>hp):   c_i = i+1 for all i with lin[i] < hc   (iup = #lin<hc)
//   down event (hc<hp): c_i = min(c_i, jdn), jdn = #lin<=hc
// b[t] = (2*sum_i Pref[i][c_i(t)] - Stot) / Stot,  Pref = row-exclusive prefix of softplus.
// Init (reference's wrap-around t=0 sweep-up with hc=1.0): rows 0..254 all +1, row 255 all -1.

#define NN 256
#define MM 4096
#define LSTEPS 16   // time steps per block in main kernel (must divide MM; batches of 16)

// ws layout (bytes):
//   0     : int   codes[MM]            (16384 B)
//   16384 : float pref[NN*(NN+3)/2]    (132608 B)

__device__ __forceinline__ int rowOff(int i) { return i * (i + 3) / 2; }

// K1 fused prep: blocks [0,NN) -> per-row softplus + exclusive prefix (wave-scan version);
//                blocks [NN, NN+MM/256) -> per-step event codes.
__global__ __launch_bounds__(NN) void k_prep(const float* __restrict__ raw,
                                             const float* __restrict__ h,
                                             const float* __restrict__ lin,
                                             float* __restrict__ pref,
                                             int* __restrict__ codes) {
    int tid = threadIdx.x;
    if (blockIdx.x < NN) {
        // ---- per-row prefix ----
        int i = blockIdx.x;
        float sp = 0.f;
        if (tid <= i) {
            float x = raw[i * (i + 1) / 2 + tid];
            sp = (x > 20.f) ? x : log1pf(expf(x));
        }
        // inclusive scan within wave64
        float v = sp;
        int lane = tid & 63, wid = tid >> 6;
        #pragma unroll
        for (int o = 1; o < 64; o <<= 1) {
            float n = __shfl_up(v, o);
            if (lane >= o) v += n;
        }
        __shared__ float wsum[4];
        if (lane == 63) wsum[wid] = v;
        __syncthreads();
        float off = 0.f;
        for (int w = 0; w < wid; ++w) off += wsum[w];
        v += off;
        int base = rowOff(i);
        if (tid == 0) pref[base] = 0.f;
        if (tid <= i) pref[base + tid + 1] = v;   // exclusive prefix: Pref[c]=sum_{j<c}
        // pref[base + i + 1] == row total
    } else {
        // ---- event codes ----
        int k = (blockIdx.x - NN) * NN + tid;
        float hc = h[k];
        float hp = (k == 0) ? 1.0f : h[k - 1];   // hs[0] = -H_MIN = 1.0
        int code;
        if (hc > hp) {
            int lo = 0, hi = NN;                  // iup = first idx with lin >= hc
            while (lo < hi) { int mid = (lo + hi) >> 1; if (lin[mid] < hc) lo = mid + 1; else hi = mid; }
            code = (lo << 16) | 0xFFFF;
        } else if (hc < hp) {
            int lo = 0, hi = NN;                  // jdn = first idx with lin > hc
            while (lo < hi) { int mid = (lo + hi) >> 1; if (lin[mid] <= hc) lo = mid + 1; else hi = mid; }
            code = lo;                            // iup = 0
        } else {
            code = 0xFFFF;                        // no event
        }
        codes[k] = code;
    }
}

// K2: block b owns time window [T, T+LSTEPS), T = b*LSTEPS. Reconstruct c(T) by a
// batched backward scan over LDS-resident codes, then forward output steps.
__global__ __launch_bounds__(NN) void k_main(const int* __restrict__ codes,
                                             const float* __restrict__ pref,
                                             float* __restrict__ out) {
    __shared__ int sc[MM];                 // 16 KB: all step codes
    __shared__ float sTot[4];
    __shared__ float sPart[LSTEPS][4];
    int tid = threadIdx.x;
    int i = tid;                           // thread == row
    int T = blockIdx.x * LSTEPS;

    for (int k = tid; k < MM; k += NN) sc[k] = codes[k];

    int base = rowOff(i);
    {   // block-reduce row totals -> Stot
        float v = pref[base + i + 1];
        v += __shfl_xor(v, 1);  v += __shfl_xor(v, 2);  v += __shfl_xor(v, 4);
        v += __shfl_xor(v, 8);  v += __shfl_xor(v, 16); v += __shfl_xor(v, 32);
        if ((tid & 63) == 0) sTot[tid >> 6] = v;
    }
    __syncthreads();
    float stot = sTot[0] + sTot[1] + sTot[2] + sTot[3];
    float inv = 1.0f / stot;

    // Backward scan, batched 16 steps per wave-exit check. Row 255 never up-flips.
    int runmin = i + 1;                    // init c_i(0)=i+1 folded in (rows 0..254)
    int c = (i == NN - 1) ? 0 : i + 1;
    bool done = (i == NN - 1);
    for (int kb = T - 16; kb >= 0; kb -= 16) {
        if (__all(done)) break;
        #pragma unroll
        for (int u = 15; u >= 0; --u) {    // descending time within batch
            int code = sc[kb + u];
            if (!done) {
                runmin = min(runmin, code & 0xFFFF);               // down events
                if (i < (code >> 16)) { c = runmin; done = true; } // last covering up
            }
        }
    }
    if (!done) c = runmin;

    // Forward output steps: one LDS barrier total.
    #pragma unroll
    for (int kk = 0; kk < LSTEPS; ++kk) {
        int code = sc[T + kk];
        int iup = code >> 16, jdn = code & 0xFFFF;
        c = (i < iup) ? (i + 1) : min(c, jdn);
        float v = pref[base + c];
        v += __shfl_xor(v, 1);  v += __shfl_xor(v, 2);  v += __shfl_xor(v, 4);
        v += __shfl_xor(v, 8);  v += __shfl_xor(v, 16); v += __shfl_xor(v, 32);
        if ((tid & 63) == 0) sPart[kk][tid >> 6] = v;
    }
    __syncthreads();
    if (tid < LSTEPS) {
        float s = sPart[tid][0] + sPart[tid][1] + sPart[tid][2] + sPart[tid][3];
        out[T + tid] = (2.f * s - stot) * inv;
    }
}

extern "C" void kernel_launch(void* const* d_in, const int* in_sizes, int n_in,
                              void* d_out, int out_size, void* d_ws, size_t ws_size,
                              hipStream_t stream) {
    const float* h   = (const float*)d_in[0];   // (M,)
    const float* raw = (const float*)d_in[1];   // (N*(N+1)/2,)
    const float* xx  = (const float*)d_in[2];   // (N,N): row 0 is lin[0..N)
    // d_in[3] = yy (lin along rows) — not needed.

    int*   codes = (int*)d_ws;
    float* pref  = (float*)((char*)d_ws + MM * sizeof(int));

    k_prep<<<NN + MM / NN, NN, 0, stream>>>(raw, h, xx, pref, codes);
    k_main<<<MM / LSTEPS, NN, 0, stream>>>(codes, pref, (float*)d_out);
}

// Round 4
// 77.467 us; speedup vs baseline: 1.5340x; 1.2902x over previous
//
#include <hip/hip_runtime.h>
#include <hip/hip_bf16.h>

// Preisach hysteresis, N=256 mesh, M=4096 steps.
// Row-compressed state: row i is +1 for j<c_i, -1 for c_i<=j<=i (single int c_i).
//   up event (hc>hp):   c_i = i+1 for all i with lin[i] < hc   (iup = #lin<hc)
//   down event (hc<hp): c_i = min(c_i, jdn), jdn = #lin<=hc
// b[t] = (2*sum_i Pref[i][c_i(t)] - Stot) / Stot,  Pref = row-exclusive prefix of softplus.
// Init (reference's wrap-around t=0 sweep-up with hc=1.0): rows 0..254 all +1, row 255 all -1.

#define NN 256
#define MM 4096
#define LSTEPS 16   // time steps per block in main kernel

// ws layout (bytes):
//   0     : int   codes[MM]            (16384 B, 16B-aligned)
//   16384 : float pref[NN*(NN+3)/2]    (132608 B)

__device__ __forceinline__ int rowOff(int i) { return i * (i + 3) / 2; }

// K1 fused prep: blocks [0,NN) -> per-row softplus + exclusive prefix (wave-scan);
//                blocks [NN, NN+MM/256) -> per-step event codes.
__global__ __launch_bounds__(NN) void k_prep(const float* __restrict__ raw,
                                             const float* __restrict__ h,
                                             const float* __restrict__ lin,
                                             float* __restrict__ pref,
                                             int* __restrict__ codes) {
    int tid = threadIdx.x;
    if (blockIdx.x < NN) {
        int i = blockIdx.x;
        float sp = 0.f;
        if (tid <= i) {
            float x = raw[i * (i + 1) / 2 + tid];
            sp = (x > 20.f) ? x : log1pf(expf(x));
        }
        float v = sp;
        int lane = tid & 63, wid = tid >> 6;
        #pragma unroll
        for (int o = 1; o < 64; o <<= 1) {
            float n = __shfl_up(v, o);
            if (lane >= o) v += n;
        }
        __shared__ float wsum[4];
        if (lane == 63) wsum[wid] = v;
        __syncthreads();
        float off = 0.f;
        for (int w = 0; w < wid; ++w) off += wsum[w];
        v += off;
        int base = rowOff(i);
        if (tid == 0) pref[base] = 0.f;
        if (tid <= i) pref[base + tid + 1] = v;   // exclusive prefix; [base+i+1] = row total
    } else {
        int k = (blockIdx.x - NN) * NN + tid;
        float hc = h[k];
        float hp = (k == 0) ? 1.0f : h[k - 1];    // hs[0] = -H_MIN = 1.0
        int code;
        if (hc > hp) {
            int lo = 0, hi = NN;                  // iup = first idx with lin >= hc
            while (lo < hi) { int mid = (lo + hi) >> 1; if (lin[mid] < hc) lo = mid + 1; else hi = mid; }
            code = (lo << 16) | 0xFFFF;
        } else if (hc < hp) {
            int lo = 0, hi = NN;                  // jdn = first idx with lin > hc
            while (lo < hi) { int mid = (lo + hi) >> 1; if (lin[mid] <= hc) lo = mid + 1; else hi = mid; }
            code = lo;                            // iup = 0
        } else {
            code = 0xFFFF;                        // no event
        }
        codes[k] = code;
    }
}

// K2: block b owns time window [T, T+LSTEPS). Reconstruct c(T) by a LOAD-FIRST,
// BRANCHLESS batched backward scan over LDS codes, then forward output steps.
__global__ __launch_bounds__(NN) void k_main(const int* __restrict__ codes,
                                             const float* __restrict__ pref,
                                             float* __restrict__ out) {
    __shared__ __align__(16) int sc[MM];   // 16 KB: all step codes
    __shared__ float sTot[4];
    __shared__ float sPart[LSTEPS][4];
    int tid = threadIdx.x;
    const int i = tid;                     // thread == row
    int T = blockIdx.x * LSTEPS;

    {   // vectorized staging: 4 x int4 per thread
        const int4* g4 = (const int4*)codes;
        int4* s4 = (int4*)sc;
        #pragma unroll
        for (int u = 0; u < MM / 4 / NN; ++u) s4[tid + u * NN] = g4[tid + u * NN];
    }

    int base = rowOff(i);
    {   // block-reduce row totals -> Stot (overlaps staging; barrier below covers both)
        float v = pref[base + i + 1];
        v += __shfl_xor(v, 1);  v += __shfl_xor(v, 2);  v += __shfl_xor(v, 4);
        v += __shfl_xor(v, 8);  v += __shfl_xor(v, 16); v += __shfl_xor(v, 32);
        if ((tid & 63) == 0) sTot[tid >> 6] = v;
    }
    __syncthreads();
    float stot = sTot[0] + sTot[1] + sTot[2] + sTot[3];
    float inv = 1.0f / stot;

    // Backward scan: per 16-step batch, load 16 codes first (4 x ds_read_b128),
    // then process branchlessly in descending time order. Row 255 never up-covered.
    int runmin = i + 1;                    // init c_i(0)=i+1 folded in (rows 0..254)
    int c = (i == NN - 1) ? 0 : i + 1;
    bool done = (i == NN - 1);
    const int4* s4 = (const int4*)sc;
    for (int kb = T - 16; kb >= 0; kb -= 16) {
        if (__all(done)) break;
        int4 w0 = s4[kb / 4 + 0];
        int4 w1 = s4[kb / 4 + 1];
        int4 w2 = s4[kb / 4 + 2];
        int4 w3 = s4[kb / 4 + 3];
        int cb[16] = { w0.x, w0.y, w0.z, w0.w, w1.x, w1.y, w1.z, w1.w,
                       w2.x, w2.y, w2.z, w2.w, w3.x, w3.y, w3.z, w3.w };
        #pragma unroll
        for (int u = 15; u >= 0; --u) {    // descending time
            int code = cb[u];
            int jd = code & 0xFFFF;
            bool cover = i < (code >> 16);
            runmin = min(runmin, jd);      // up events carry jd=0xFFFF: harmless
            c = (cover && !done) ? runmin : c;   // select BEFORE done update
            done = done || cover;
        }
    }
    if (!done) c = runmin;

    // Forward: compute all 16 states + issue all 16 gathers, then reduce.
    float vals[LSTEPS];
    #pragma unroll
    for (int kk = 0; kk < LSTEPS; ++kk) {
        int code = sc[T + kk];
        c = (i < (code >> 16)) ? (i + 1) : min(c, code & 0xFFFF);
        vals[kk] = pref[base + c];
    }
    #pragma unroll
    for (int kk = 0; kk < LSTEPS; ++kk) {
        float v = vals[kk];
        v += __shfl_xor(v, 1);  v += __shfl_xor(v, 2);  v += __shfl_xor(v, 4);
        v += __shfl_xor(v, 8);  v += __shfl_xor(v, 16); v += __shfl_xor(v, 32);
        if ((tid & 63) == 0) sPart[kk][tid >> 6] = v;
    }
    __syncthreads();
    if (tid < LSTEPS) {
        float s = sPart[tid][0] + sPart[tid][1] + sPart[tid][2] + sPart[tid][3];
        out[T + tid] = (2.f * s - stot) * inv;
    }
}

extern "C" void kernel_launch(void* const* d_in, const int* in_sizes, int n_in,
                              void* d_out, int out_size, void* d_ws, size_t ws_size,
                              hipStream_t stream) {
    const float* h   = (const float*)d_in[0];   // (M,)
    const float* raw = (const float*)d_in[1];   // (N*(N+1)/2,)
    const float* xx  = (const float*)d_in[2];   // (N,N): row 0 is lin[0..N)
    // d_in[3] = yy (lin along rows) — not needed.

    int*   codes = (int*)d_ws;
    float* pref  = (float*)((char*)d_ws + MM * sizeof(int));

    k_prep<<<NN + MM / NN, NN, 0, stream>>>(raw, h, xx, pref, codes);
    k_main<<<MM / LSTEPS, NN, 0, stream>>>(codes, pref, (float*)d_out);
}

// Round 5
// 72.318 us; speedup vs baseline: 1.6432x; 1.0712x over previous
//
#include <hip/hip_runtime.h>
#include <hip/hip_bf16.h>

// Preisach hysteresis, N=256 mesh, M=4096 steps.
// Row-compressed state: row i is +1 for j<c_i, -1 for c_i<=j<=i (single int c_i).
//   up event (hc>hp):   c_i = i+1 for all i with lin[i] < hc   (iup = #lin<hc)
//   down event (hc<hp): c_i = min(c_i, jdn), jdn = #lin<=hc
// b[t] = (2*sum_i Pref[i][c_i(t)] - Stot) / Stot,  Pref = row-exclusive prefix of softplus.
// Init (reference's wrap-around t=0 sweep-up, hc=1.0): rows 0..254 all +1, row 255 all -1.
//
// R5: 16-step chunk aggregates ((max_iup<<16)|min_jdn) let the backward scan skip a
// whole chunk in ~3 ops, descending per-step only where a covering up-event lies.

#define NN 256
#define MM 4096
#define LSTEPS 16          // time steps per block == aggregate chunk size
#define NCHUNK (MM / LSTEPS)

// ws layout (bytes):
//   0     : int   codes[MM]    (16384 B, 16B-aligned)
//   16384 : int   agg[NCHUNK]  (1024 B)
//   17408 : float pref[NN*(NN+3)/2]  (132608 B)

__device__ __forceinline__ int rowOff(int i) { return i * (i + 3) / 2; }

// K1 fused prep: blocks [0,NN) -> per-row softplus + exclusive prefix (wave-scan);
//                blocks [NN, NN+MM/256) -> per-step event codes + 16-step aggregates.
__global__ __launch_bounds__(NN) void k_prep(const float* __restrict__ raw,
                                             const float* __restrict__ h,
                                             const float* __restrict__ lin,
                                             float* __restrict__ pref,
                                             int* __restrict__ codes,
                                             int* __restrict__ agg) {
    int tid = threadIdx.x;
    if (blockIdx.x < NN) {
        int i = blockIdx.x;
        float sp = 0.f;
        if (tid <= i) {
            float x = raw[i * (i + 1) / 2 + tid];
            sp = (x > 20.f) ? x : log1pf(expf(x));
        }
        float v = sp;
        int lane = tid & 63, wid = tid >> 6;
        #pragma unroll
        for (int o = 1; o < 64; o <<= 1) {
            float n = __shfl_up(v, o);
            if (lane >= o) v += n;
        }
        __shared__ float wsum[4];
        if (lane == 63) wsum[wid] = v;
        __syncthreads();
        float off = 0.f;
        for (int w = 0; w < wid; ++w) off += wsum[w];
        v += off;
        int base = rowOff(i);
        if (tid == 0) pref[base] = 0.f;
        if (tid <= i) pref[base + tid + 1] = v;   // exclusive prefix; [base+i+1] = row total
    } else {
        int k = (blockIdx.x - NN) * NN + tid;
        float hc = h[k];
        float hp = (k == 0) ? 1.0f : h[k - 1];    // hs[0] = -H_MIN = 1.0
        int code;
        if (hc > hp) {
            int lo = 0, hi = NN;                  // iup = first idx with lin >= hc
            while (lo < hi) { int mid = (lo + hi) >> 1; if (lin[mid] < hc) lo = mid + 1; else hi = mid; }
            code = (lo << 16) | 0xFFFF;
        } else if (hc < hp) {
            int lo = 0, hi = NN;                  // jdn = first idx with lin > hc
            while (lo < hi) { int mid = (lo + hi) >> 1; if (lin[mid] <= hc) lo = mid + 1; else hi = mid; }
            code = lo;                            // iup = 0
        } else {
            code = 0xFFFF;                        // no event
        }
        codes[k] = code;
        // 16-step chunk aggregate via intra-16-lane shuffle reduce.
        int iup = code >> 16, jdn = code & 0xFFFF;
        #pragma unroll
        for (int m = 1; m < 16; m <<= 1) {
            iup = max(iup, __shfl_xor(iup, m));
            jdn = min(jdn, __shfl_xor(jdn, m));
        }
        if ((tid & 15) == 0) agg[k >> 4] = (iup << 16) | jdn;
    }
}

// K2: block b owns steps [T, T+16), T = 16*b. Backward scan over chunk aggregates
// with per-step descent only into covering chunks; then forward gathers + reduce.
__global__ __launch_bounds__(NN) void k_main(const int* __restrict__ codes,
                                             const int* __restrict__ aggG,
                                             const float* __restrict__ pref,
                                             float* __restrict__ out) {
    __shared__ __align__(16) int sc[MM];       // 16 KB: all step codes
    __shared__ int sagg[NCHUNK];               // 1 KB: chunk aggregates
    __shared__ float sPart[LSTEPS + 1][4];     // 16 step-partials + Stot partials
    int tid = threadIdx.x;
    const int i = tid;                         // thread == row
    const int T = blockIdx.x * LSTEPS;

    int base = rowOff(i);
    float rowtot = pref[base + i + 1];         // issue early; used after barrier

    {   // vectorized staging: 4 x int4 per thread + 1 agg int
        const int4* g4 = (const int4*)codes;
        int4* d4 = (int4*)sc;
        #pragma unroll
        for (int u = 0; u < MM / 4 / NN; ++u) d4[tid + u * NN] = g4[tid + u * NN];
        sagg[tid] = aggG[tid];
    }
    __syncthreads();

    // Backward scan. Row 255 never up-covered (lin[255]=1.0 > h).
    int runmin = i + 1;                        // init c_i(0)=i+1 folded in (rows 0..254)
    int c = (i == NN - 1) ? 0 : i + 1;
    bool done = (i == NN - 1);
    const int4* s4 = (const int4*)sc;
    for (int j = blockIdx.x - 1; j >= 0; --j) {
        if (__all(done)) break;
        int ag = sagg[j];
        bool want = (!done) && (i < (ag >> 16));
        if (__any(want)) {
            // descend: process chunk j per-step (branchless); lanes without a
            // covering event here just accumulate the chunk-min step by step.
            int4 w0 = s4[j * 4 + 0];
            int4 w1 = s4[j * 4 + 1];
            int4 w2 = s4[j * 4 + 2];
            int4 w3 = s4[j * 4 + 3];
            int cb[16] = { w0.x, w0.y, w0.z, w0.w, w1.x, w1.y, w1.z, w1.w,
                           w2.x, w2.y, w2.z, w2.w, w3.x, w3.y, w3.z, w3.w };
            #pragma unroll
            for (int u = 15; u >= 0; --u) {    // descending time
                int code = cb[u];
                bool cover = i < (code >> 16);
                runmin = min(runmin, code & 0xFFFF);   // up steps carry 0xFFFF: harmless
                c = (cover && !done) ? runmin : c;
                done = done || cover;
            }
        } else {
            runmin = min(runmin, ag & 0xFFFF);         // skip whole chunk
        }
    }
    if (!done) c = runmin;

    // Forward: compute 16 states, issue 16 gathers (c-chain is short; loads overlap).
    int4 f0 = s4[blockIdx.x * 4 + 0];
    int4 f1 = s4[blockIdx.x * 4 + 1];
    int4 f2 = s4[blockIdx.x * 4 + 2];
    int4 f3 = s4[blockIdx.x * 4 + 3];
    int fc[16] = { f0.x, f0.y, f0.z, f0.w, f1.x, f1.y, f1.z, f1.w,
                   f2.x, f2.y, f2.z, f2.w, f3.x, f3.y, f3.z, f3.w };
    float vals[LSTEPS];
    #pragma unroll
    for (int kk = 0; kk < LSTEPS; ++kk) {
        int code = fc[kk];
        c = (i < (code >> 16)) ? (i + 1) : min(c, code & 0xFFFF);
        vals[kk] = pref[base + c];
    }
    // Reduce 16 step-sums + Stot (sum of row totals) in one pass.
    #pragma unroll
    for (int kk = 0; kk <= LSTEPS; ++kk) {
        float v = (kk < LSTEPS) ? vals[kk] : rowtot;
        v += __shfl_xor(v, 1);  v += __shfl_xor(v, 2);  v += __shfl_xor(v, 4);
        v += __shfl_xor(v, 8);  v += __shfl_xor(v, 16); v += __shfl_xor(v, 32);
        if ((tid & 63) == 0) sPart[kk][tid >> 6] = v;
    }
    __syncthreads();
    if (tid < LSTEPS) {
        float s  = sPart[tid][0] + sPart[tid][1] + sPart[tid][2] + sPart[tid][3];
        float st = sPart[LSTEPS][0] + sPart[LSTEPS][1] + sPart[LSTEPS][2] + sPart[LSTEPS][3];
        out[T + tid] = (2.f * s - st) / st;
    }
}

extern "C" void kernel_launch(void* const* d_in, const int* in_sizes, int n_in,
                              void* d_out, int out_size, void* d_ws, size_t ws_size,
                              hipStream_t stream) {
    const float* h   = (const float*)d_in[0];   // (M,)
    const float* raw = (const float*)d_in[1];   // (N*(N+1)/2,)
    const float* xx  = (const float*)d_in[2];   // (N,N): row 0 is lin[0..N)
    // d_in[3] = yy (lin along rows) — not needed.

    int*   codes = (int*)d_ws;
    int*   agg   = (int*)((char*)d_ws + 16384);
    float* pref  = (float*)((char*)d_ws + 17408);

    k_prep<<<NN + MM / NN, NN, 0, stream>>>(raw, h, xx, pref, codes, agg);
    k_main<<<MM / LSTEPS, NN, 0, stream>>>(codes, agg, pref, (float*)d_out);
}

// Round 6
// 68.779 us; speedup vs baseline: 1.7278x; 1.0515x over previous
//
#include <hip/hip_runtime.h>
#include <hip/hip_bf16.h>

// Preisach hysteresis, N=256 mesh, M=4096 steps.
// Row-compressed state: row i is +1 for j<c_i, -1 for c_i<=j<=i (single int c_i).
//   up event (hc>hp):   c_i = i+1 for all i with lin[i] < hc   (iup = #lin<hc)
//   down event (hc<hp): c_i = min(c_i, jdn), jdn = #lin<=hc
// b[t] = (2*sum_i Pref[i][c_i(t)] - Stot) / Stot,  Pref = row-exclusive prefix of softplus.
// Init (reference's wrap-around t=0 sweep-up, hc=1.0): rows 0..254 all +1, row 255 all -1.
//
// R6: (a) codes via double-precision arithmetic guess + exact LDS-lin verify (kills the
// 8-deep dependent-load binary search); (b) backward scan batches 16 chunk-aggregates
// per iteration (4 x ds_read_b128, branchless skim) — descends only where needed.

#define NN 256
#define MM 4096
#define LSTEPS 16          // time steps per block == aggregate chunk size
#define NCHUNK (MM / LSTEPS)

// ws layout (bytes):
//   0     : int   codes[MM]    (16384 B, 16B-aligned)
//   16384 : int   agg[NCHUNK]  (1024 B)
//   17408 : float pref[NN*(NN+3)/2]  (132608 B)

__device__ __forceinline__ int rowOff(int i) { return i * (i + 3) / 2; }

// K1 fused prep: blocks [0,NN) -> per-row softplus + exclusive prefix (wave-scan);
//                blocks [NN, NN+MM/256) -> per-step event codes + 16-step aggregates.
__global__ __launch_bounds__(NN) void k_prep(const float* __restrict__ raw,
                                             const float* __restrict__ h,
                                             const float* __restrict__ lin,
                                             float* __restrict__ pref,
                                             int* __restrict__ codes,
                                             int* __restrict__ agg) {
    int tid = threadIdx.x;
    if (blockIdx.x < NN) {
        int i = blockIdx.x;
        float sp = 0.f;
        if (tid <= i) {
            float x = raw[i * (i + 1) / 2 + tid];
            sp = (x > 20.f) ? x : log1pf(expf(x));
        }
        float v = sp;
        int lane = tid & 63, wid = tid >> 6;
        #pragma unroll
        for (int o = 1; o < 64; o <<= 1) {
            float n = __shfl_up(v, o);
            if (lane >= o) v += n;
        }
        __shared__ float wsum[4];
        if (lane == 63) wsum[wid] = v;
        __syncthreads();
        float off = 0.f;
        for (int w = 0; w < wid; ++w) off += wsum[w];
        v += off;
        int base = rowOff(i);
        if (tid == 0) pref[base] = 0.f;
        if (tid <= i) pref[base + tid + 1] = v;   // exclusive prefix; [base+i+1] = row total
    } else {
        __shared__ float slin[NN];
        slin[tid] = lin[tid];
        __syncthreads();
        int k = (blockIdx.x - NN) * NN + tid;
        float hc = h[k];
        float hp = (k == 0) ? 1.0f : h[k - 1];    // hs[0] = -H_MIN = 1.0
        // arithmetic index guess (lin ~ linspace(-1,1,256)), then exact fp32 verify
        double td = ((double)hc + 1.0) * 127.5;
        int code;
        if (hc > hp) {
            int g = (int)ceil(td);                // iup = #{lin < hc}
            while (g < NN && slin[g] < hc) ++g;   // executes 0..1 times
            while (g > 0 && slin[g - 1] >= hc) --g;
            code = (g << 16) | 0xFFFF;
        } else if (hc < hp) {
            int g = (int)floor(td) + 1;           // jdn = #{lin <= hc}
            while (g < NN && slin[g] <= hc) ++g;
            while (g > 0 && slin[g - 1] > hc) --g;
            code = g;                             // iup = 0
        } else {
            code = 0xFFFF;                        // no event
        }
        codes[k] = code;
        // 16-step chunk aggregate via intra-16-lane shuffle reduce.
        int iup = code >> 16, jdn = code & 0xFFFF;
        #pragma unroll
        for (int m = 1; m < 16; m <<= 1) {
            iup = max(iup, __shfl_xor(iup, m));
            jdn = min(jdn, __shfl_xor(jdn, m));
        }
        if ((tid & 15) == 0) agg[k >> 4] = (iup << 16) | jdn;
    }
}

// K2: block b owns steps [T, T+16). Backward scan over chunk aggregates, batched 16
// aggs per iteration; per-chunk / per-step descent only where a covering event lies.
__global__ __launch_bounds__(NN) void k_main(const int* __restrict__ codes,
                                             const int* __restrict__ aggG,
                                             const float* __restrict__ pref,
                                             float* __restrict__ out) {
    __shared__ __align__(16) int sc[MM];       // 16 KB: all step codes
    __shared__ __align__(16) int sagg[NCHUNK]; // 1 KB: chunk aggregates
    __shared__ float sPart[LSTEPS + 1][4];
    int tid = threadIdx.x;
    const int i = tid;                         // thread == row
    const int T = blockIdx.x * LSTEPS;

    int base = rowOff(i);
    float rowtot = pref[base + i + 1];         // issue early; used after barrier

    {   // vectorized staging
        const int4* g4 = (const int4*)codes;
        int4* d4 = (int4*)sc;
        #pragma unroll
        for (int u = 0; u < MM / 4 / NN; ++u) d4[tid + u * NN] = g4[tid + u * NN];
        sagg[tid] = aggG[tid];
    }
    __syncthreads();

    // Backward scan. Row 255 never up-covered (lin[255]=1.0 > h).
    int runmin = i + 1;                        // init c_i(0)=i+1 folded in (rows 0..254)
    int c = (i == NN - 1) ? 0 : i + 1;
    bool done = (i == NN - 1);
    const int4* s4 = (const int4*)sc;
    const int4* a4 = (const int4*)sagg;
    const int jlim = blockIdx.x - 1;           // most recent history chunk
    for (int jb = (jlim >> 4) << 4; jb >= 0; jb -= 16) {   // 16-chunk batches
        if (__all(done)) break;
        int4 A0 = a4[jb / 4 + 0];
        int4 A1 = a4[jb / 4 + 1];
        int4 A2 = a4[jb / 4 + 2];
        int4 A3 = a4[jb / 4 + 3];
        int ag[16] = { A0.x, A0.y, A0.z, A0.w, A1.x, A1.y, A1.z, A1.w,
                       A2.x, A2.y, A2.z, A2.w, A3.x, A3.y, A3.z, A3.w };
        // neutralize future chunks (only possible in the first batch)
        #pragma unroll
        for (int u = 0; u < 16; ++u) if (jb + u > jlim) ag[u] = 0xFFFF;
        // branchless skim: does any lane need any chunk in this batch?
        bool anyw = false; int bmin = 0xFFFF;
        #pragma unroll
        for (int u = 0; u < 16; ++u) {
            anyw = anyw || (!done && (i < (ag[u] >> 16)));
            bmin = min(bmin, ag[u] & 0xFFFF);
        }
        if (__any(anyw)) {
            // per-chunk pass, descending time
            #pragma unroll
            for (int u = 15; u >= 0; --u) {
                int a = ag[u];
                bool want = !done && (i < (a >> 16));
                if (__any(want)) {
                    int q = jb + u;
                    int4 w0 = s4[q * 4 + 0];
                    int4 w1 = s4[q * 4 + 1];
                    int4 w2 = s4[q * 4 + 2];
                    int4 w3 = s4[q * 4 + 3];
                    int cb[16] = { w0.x, w0.y, w0.z, w0.w, w1.x, w1.y, w1.z, w1.w,
                                   w2.x, w2.y, w2.z, w2.w, w3.x, w3.y, w3.z, w3.w };
                    #pragma unroll
                    for (int s = 15; s >= 0; --s) {        // descending time
                        int code = cb[s];
                        bool cover = i < (code >> 16);
                        runmin = min(runmin, code & 0xFFFF);
                        c = (cover && !done) ? runmin : c;
                        done = done || cover;
                    }
                } else {
                    runmin = min(runmin, a & 0xFFFF);
                }
            }
        } else {
            runmin = min(runmin, bmin);        // skip 256 steps in one go
        }
    }
    if (!done) c = runmin;

    // Forward: compute 16 states, issue 16 gathers, then one fused reduction pass.
    int4 f0 = s4[blockIdx.x * 4 + 0];
    int4 f1 = s4[blockIdx.x * 4 + 1];
    int4 f2 = s4[blockIdx.x * 4 + 2];
    int4 f3 = s4[blockIdx.x * 4 + 3];
    int fc[16] = { f0.x, f0.y, f0.z, f0.w, f1.x, f1.y, f1.z, f1.w,
                   f2.x, f2.y, f2.z, f2.w, f3.x, f3.y, f3.z, f3.w };
    float vals[LSTEPS];
    #pragma unroll
    for (int kk = 0; kk < LSTEPS; ++kk) {
        int code = fc[kk];
        c = (i < (code >> 16)) ? (i + 1) : min(c, code & 0xFFFF);
        vals[kk] = pref[base + c];
    }
    #pragma unroll
    for (int kk = 0; kk <= LSTEPS; ++kk) {
        float v = (kk < LSTEPS) ? vals[kk] : rowtot;
        v += __shfl_xor(v, 1);  v += __shfl_xor(v, 2);  v += __shfl_xor(v, 4);
        v += __shfl_xor(v, 8);  v += __shfl_xor(v, 16); v += __shfl_xor(v, 32);
        if ((tid & 63) == 0) sPart[kk][tid >> 6] = v;
    }
    __syncthreads();
    if (tid < LSTEPS) {
        float s  = sPart[tid][0] + sPart[tid][1] + sPart[tid][2] + sPart[tid][3];
        float st = sPart[LSTEPS][0] + sPart[LSTEPS][1] + sPart[LSTEPS][2] + sPart[LSTEPS][3];
        out[T + tid] = (2.f * s - st) / st;
    }
}

extern "C" void kernel_launch(void* const* d_in, const int* in_sizes, int n_in,
                              void* d_out, int out_size, void* d_ws, size_t ws_size,
                              hipStream_t stream) {
    const float* h   = (const float*)d_in[0];   // (M,)
    const float* raw = (const float*)d_in[1];   // (N*(N+1)/2,)
    const float* xx  = (const float*)d_in[2];   // (N,N): row 0 is lin[0..N)
    // d_in[3] = yy (lin along rows) — not needed.

    int*   codes = (int*)d_ws;
    int*   agg   = (int*)((char*)d_ws + 16384);
    float* pref  = (float*)((char*)d_ws + 17408);

    k_prep<<<NN + MM / NN, NN, 0, stream>>>(raw, h, xx, pref, codes, agg);
    k_main<<<MM / LSTEPS, NN, 0, stream>>>(codes, agg, pref, (float*)d_out);
}